// Round 1
// baseline (254.977 us; speedup 1.0000x reference)
//
#include <hip/hip_runtime.h>
#include <stdint.h>

typedef unsigned short u16;
typedef unsigned int   u32;
typedef unsigned char  u8;
typedef __attribute__((ext_vector_type(4))) float f32x4;
typedef __attribute__((ext_vector_type(8))) __bf16 bf16x8;

#define MFMA16(a, b, c) __builtin_amdgcn_mfma_f32_16x16x32_bf16((a), (b), (c), 0, 0, 0)

__device__ __forceinline__ u16 f2bf(float f) {
  u32 u = __float_as_uint(f);
  return (u16)((u + 0x7fffu + ((u >> 16) & 1u)) >> 16);  // RNE
}

__device__ __forceinline__ void gl_lds16(const void* g, void* l) {
  __builtin_amdgcn_global_load_lds((const __attribute__((address_space(1))) u32*)g,
                                   (__attribute__((address_space(3))) u32*)l, 16, 0, 0);
}

// ---------------- f32 -> bf16 converters ----------------
__global__ void __launch_bounds__(256) cvt3_kernel(const float4* __restrict__ a, const float4* __restrict__ b,
                                                   const float4* __restrict__ c, ushort4* __restrict__ oa,
                                                   ushort4* __restrict__ ob, ushort4* __restrict__ oc, int n4) {
  int i = blockIdx.x * 256 + threadIdx.x;
  if (i >= n4) return;
  float4 v;
  v = a[i]; oa[i] = make_ushort4(f2bf(v.x), f2bf(v.y), f2bf(v.z), f2bf(v.w));
  v = b[i]; ob[i] = make_ushort4(f2bf(v.x), f2bf(v.y), f2bf(v.z), f2bf(v.w));
  v = c[i]; oc[i] = make_ushort4(f2bf(v.x), f2bf(v.y), f2bf(v.z), f2bf(v.w));
}

__global__ void __launch_bounds__(256) cvt4_kernel(const float4* __restrict__ a, const float4* __restrict__ b,
                                                   const float4* __restrict__ c, const float4* __restrict__ d,
                                                   ushort4* __restrict__ oa, ushort4* __restrict__ ob,
                                                   ushort4* __restrict__ oc, ushort4* __restrict__ od, int n4) {
  int i = blockIdx.x * 256 + threadIdx.x;
  if (i >= n4) return;
  float4 v;
  v = a[i]; oa[i] = make_ushort4(f2bf(v.x), f2bf(v.y), f2bf(v.z), f2bf(v.w));
  v = b[i]; ob[i] = make_ushort4(f2bf(v.x), f2bf(v.y), f2bf(v.z), f2bf(v.w));
  v = c[i]; oc[i] = make_ushort4(f2bf(v.x), f2bf(v.y), f2bf(v.z), f2bf(v.w));
  v = d[i]; od[i] = make_ushort4(f2bf(v.x), f2bf(v.y), f2bf(v.z), f2bf(v.w));
}

// ---------------- pack 5 boolean matrices into bytes, transposed [b][k][q] ----------------
__device__ __forceinline__ u32 pbit(float t, float s, float d, float c, int m) {
  return (t != 0.0f ? 1u : 0u) | (s != 0.0f ? 2u : 0u) | (d != 0.0f ? 4u : 0u) |
         (c != 0.0f ? 8u : 0u) | (m != 0 ? 16u : 0u);
}

__global__ void __launch_bounds__(256) pack_kernel(const float4* __restrict__ tok, const float4* __restrict__ st,
                                                   const float4* __restrict__ df, const float4* __restrict__ cf,
                                                   const int4* __restrict__ msk, u8* __restrict__ out) {
  __shared__ u8 tile[64][68];
  const int t = threadIdx.x;
  const int b = blockIdx.z;
  const int q0 = blockIdx.y * 64, k0 = blockIdx.x * 64;
  const int qr = t >> 2, kc = (t & 3) * 16;
  size_t rb = ((size_t)b * 1048576 + (size_t)(q0 + qr) * 1024 + k0 + kc) >> 2;  // float4 index
#pragma unroll
  for (int j = 0; j < 4; j++) {
    float4 vt = tok[rb + j], vs = st[rb + j], vd = df[rb + j], vc = cf[rb + j];
    int4 vm = msk[rb + j];
    u32 b0 = pbit(vt.x, vs.x, vd.x, vc.x, vm.x);
    u32 b1 = pbit(vt.y, vs.y, vd.y, vc.y, vm.y);
    u32 b2 = pbit(vt.z, vs.z, vd.z, vc.z, vm.z);
    u32 b3 = pbit(vt.w, vs.w, vd.w, vc.w, vm.w);
    *(u32*)&tile[qr][kc + j * 4] = b0 | (b1 << 8) | (b2 << 16) | (b3 << 24);
  }
  __syncthreads();
  const int kr = t >> 2, qc = (t & 3) * 16;
  u32 wds[4];
#pragma unroll
  for (int j2 = 0; j2 < 4; j2++) {
    u32 acc = 0;
#pragma unroll
    for (int j = 0; j < 4; j++) acc |= ((u32)tile[qc + j2 * 4 + j][kr]) << (8 * j);
    wds[j2] = acc;
  }
  size_t ob = (size_t)b * 1048576 + (size_t)(k0 + kr) * 1024 + q0 + qc;
  *(uint4*)(out + ob) = make_uint4(wds[0], wds[1], wds[2], wds[3]);
}

// ---------------- bf16 GEMM: C[m][n] = sum_k A[m][k]*W[n][k] + bias[n] ----------------
// MODE 0: write bf16 head-major  Qh/Kh[(b*16+h)*65536 + s*64 + d]
// MODE 2: write bf16 transposed  VhT[(b*16+h)*65536 + d*1024 + s]
// MODE 3: write f32 plain        out[m*1024 + n]
template <int MODE>
__global__ void __launch_bounds__(256) gemm_bt(const u16* __restrict__ A, const u16* __restrict__ W,
                                               const float* __restrict__ bias, void* __restrict__ Out) {
  __shared__ u16 smA[128 * 32];
  __shared__ u16 smB[128 * 32];
  const int t = threadIdx.x;
  const int w = t >> 6, l = t & 63;
  const int l15 = l & 15, lg = l >> 4;
  const int m0 = blockIdx.y * 128, n0 = blockIdx.x * 128;
  const int wr = w >> 1, wc = w & 1;
  f32x4 acc[4][4] = {};
  const int srow = w * 16 + (l >> 2);
  const int scol = (l & 3) * 8;
  const u16* Ab = A + (size_t)(m0 + srow) * 1024 + scol;
  const u16* Wb = W + (size_t)(n0 + srow) * 1024 + scol;
  u16* sA0 = smA + srow * 32 + scol;
  u16* sB0 = smB + srow * 32 + scol;
  for (int kk = 0; kk < 1024; kk += 32) {
    gl_lds16(Ab + kk, sA0);
    gl_lds16(Ab + kk + (size_t)64 * 1024, sA0 + 64 * 32);
    gl_lds16(Wb + kk, sB0);
    gl_lds16(Wb + kk + (size_t)64 * 1024, sB0 + 64 * 32);
    __syncthreads();
    bf16x8 af[4], bv[4];
#pragma unroll
    for (int i = 0; i < 4; i++) af[i] = *(const bf16x8*)(smA + (wr * 64 + i * 16 + l15) * 32 + lg * 8);
#pragma unroll
    for (int i = 0; i < 4; i++) bv[i] = *(const bf16x8*)(smB + (wc * 64 + i * 16 + l15) * 32 + lg * 8);
#pragma unroll
    for (int i = 0; i < 4; i++)
#pragma unroll
      for (int j = 0; j < 4; j++) acc[i][j] = MFMA16(af[i], bv[j], acc[i][j]);
    __syncthreads();
  }
#pragma unroll
  for (int j = 0; j < 4; j++) {
    const int n = n0 + wc * 64 + j * 16 + l15;
    const float bvj = bias[n];
#pragma unroll
    for (int i = 0; i < 4; i++) {
      const int mbase = m0 + wr * 64 + i * 16 + lg * 4;
      if (MODE == 0) {
        u16* o = (u16*)Out;
#pragma unroll
        for (int r = 0; r < 4; r++) {
          const int m = mbase + r;
          o[((size_t)((m >> 10) * 16 + (n >> 6)) << 16) + (size_t)(m & 1023) * 64 + (n & 63)] =
              f2bf(acc[i][j][r] + bvj);
        }
      } else if (MODE == 2) {
        u16* o = (u16*)Out;
        size_t off = ((size_t)((mbase >> 10) * 16 + (n >> 6)) << 16) + (size_t)(n & 63) * 1024 + (mbase & 1023);
        *(ushort4*)(o + off) = make_ushort4(f2bf(acc[i][j][0] + bvj), f2bf(acc[i][j][1] + bvj),
                                            f2bf(acc[i][j][2] + bvj), f2bf(acc[i][j][3] + bvj));
      } else {
        float* o = (float*)Out;
#pragma unroll
        for (int r = 0; r < 4; r++) o[(size_t)(mbase + r) * 1024 + n] = acc[i][j][r] + bvj;
      }
    }
  }
}

// ---------------- flash attention with packed masks ----------------
__global__ void __launch_bounds__(256) attn_kernel(const u16* __restrict__ Qp, const u16* __restrict__ Kp,
                                                   const u16* __restrict__ Vt, const u8* __restrict__ packT,
                                                   u16* __restrict__ ctx) {
  __shared__ u16 pl[4][32 * 72];  // per-wave P tile, padded stride 72
  const int t = threadIdx.x;
  const int w = t >> 6, l = t & 63;
  const int l15 = l & 15, lg = l >> 4;
  const int bh = blockIdx.y;
  const int b = bh >> 4, h = bh & 15;
  const int q0 = blockIdx.x * 128 + w * 32;
  const u32 mbit = (h < 4) ? 1u : (h < 8) ? 2u : 0u;
  const u32 ebit = (h >= 8 && h < 10) ? 4u : (h >= 10 && h < 12) ? 8u : 0u;
  const size_t hb = (size_t)bh << 16;
  u16* mypl = &pl[w][0];

  bf16x8 qf[2][2];
#pragma unroll
  for (int mq = 0; mq < 2; mq++)
#pragma unroll
    for (int ks = 0; ks < 2; ks++)
      qf[mq][ks] = *(const bf16x8*)(Qp + hb + (size_t)(q0 + mq * 16 + l15) * 64 + ks * 32 + lg * 8);

  f32x4 octx[2][4] = {};
  f32x4 mrun[2] = {{-3.0e38f, -3.0e38f, -3.0e38f, -3.0e38f}, {-3.0e38f, -3.0e38f, -3.0e38f, -3.0e38f}};
  f32x4 lrun[2] = {{0.f, 0.f, 0.f, 0.f}, {0.f, 0.f, 0.f, 0.f}};
  const u8* pkb = packT + (size_t)b * 1048576 + q0;

  for (int kb = 0; kb < 1024; kb += 64) {
    // QK^T
    f32x4 sc[2][4];
#pragma unroll
    for (int nk = 0; nk < 4; nk++) {
      const u16* kp = Kp + hb + (size_t)(kb + nk * 16 + l15) * 64 + lg * 8;
      bf16x8 kf0 = *(const bf16x8*)(kp);
      bf16x8 kf1 = *(const bf16x8*)(kp + 32);
#pragma unroll
      for (int mq = 0; mq < 2; mq++) {
        f32x4 z = {0.0f, 0.0f, 0.0f, 0.0f};
        z = MFMA16(qf[mq][0], kf0, z);
        z = MFMA16(qf[mq][1], kf1, z);
        sc[mq][nk] = z;
      }
    }
    // packed mask bytes: 4 consecutive q (=C-fragment rows) per u32
    u32 pk[2][4];
#pragma unroll
    for (int mq = 0; mq < 2; mq++)
#pragma unroll
      for (int nk = 0; nk < 4; nk++)
        pk[mq][nk] = *(const u32*)(pkb + (size_t)(kb + nk * 16 + l15) * 1024 + mq * 16 + lg * 4);
    // apply masks + online softmax
    f32x4 scale[2];
#pragma unroll
    for (int mq = 0; mq < 2; mq++) {
#pragma unroll
      for (int r = 0; r < 4; r++) {
        float smax = -3.0e38f;
#pragma unroll
        for (int nk = 0; nk < 4; nk++) {
          float s = sc[mq][nk][r] * 0.125f;
          u32 pb = (pk[mq][nk] >> (r * 8)) & 0xffu;
          s += (pb & mbit) ? -1.0e9f : 0.0f;
          s += (pb & ebit) ? 5.0f * fabsf(s) : 0.0f;
          s = (pb & 16u) ? s : -1.0e9f;
          sc[mq][nk][r] = s;
          smax = fmaxf(smax, s);
        }
#pragma unroll
        for (int off = 1; off < 16; off <<= 1) smax = fmaxf(smax, __shfl_xor(smax, off));
        float mo = mrun[mq][r];
        float mn = fmaxf(mo, smax);
        float so = __expf(mo - mn);
        float psum = 0.0f;
#pragma unroll
        for (int nk = 0; nk < 4; nk++) {
          float p = __expf(sc[mq][nk][r] - mn);
          sc[mq][nk][r] = p;
          psum += p;
        }
#pragma unroll
        for (int off = 1; off < 16; off <<= 1) psum += __shfl_xor(psum, off);
        lrun[mq][r] = lrun[mq][r] * so + psum;
        mrun[mq][r] = mn;
        scale[mq][r] = so;
      }
    }
    // rescale accumulated context
#pragma unroll
    for (int mq = 0; mq < 2; mq++)
#pragma unroll
      for (int nd = 0; nd < 4; nd++)
#pragma unroll
        for (int r = 0; r < 4; r++) octx[mq][nd][r] *= scale[mq][r];
    // P -> LDS (bf16)
#pragma unroll
    for (int mq = 0; mq < 2; mq++)
#pragma unroll
      for (int nk = 0; nk < 4; nk++)
#pragma unroll
        for (int r = 0; r < 4; r++)
          mypl[(mq * 16 + lg * 4 + r) * 72 + nk * 16 + l15] = f2bf(sc[mq][nk][r]);
    // PV
#pragma unroll
    for (int kk = 0; kk < 2; kk++) {
      bf16x8 pa0 = *(const bf16x8*)(mypl + (0 * 16 + l15) * 72 + kk * 32 + lg * 8);
      bf16x8 pa1 = *(const bf16x8*)(mypl + (1 * 16 + l15) * 72 + kk * 32 + lg * 8);
#pragma unroll
      for (int nd = 0; nd < 4; nd++) {
        bf16x8 vf = *(const bf16x8*)(Vt + hb + (size_t)(nd * 16 + l15) * 1024 + kb + kk * 32 + lg * 8);
        octx[0][nd] = MFMA16(pa0, vf, octx[0][nd]);
        octx[1][nd] = MFMA16(pa1, vf, octx[1][nd]);
      }
    }
  }
  // epilogue: normalize + store ctx bf16 at [b][s][h*64+d]
#pragma unroll
  for (int mq = 0; mq < 2; mq++) {
    f32x4 inv;
#pragma unroll
    for (int r = 0; r < 4; r++) inv[r] = 1.0f / lrun[mq][r];
#pragma unroll
    for (int nd = 0; nd < 4; nd++)
#pragma unroll
      for (int r = 0; r < 4; r++) {
        float v = octx[mq][nd][r] * inv[r];
        ctx[(size_t)b * 1048576 + (size_t)(q0 + mq * 16 + lg * 4 + r) * 1024 + h * 64 + nd * 16 + l15] = f2bf(v);
      }
  }
}

extern "C" void kernel_launch(void* const* d_in, const int* in_sizes, int n_in,
                              void* d_out, int out_size, void* d_ws, size_t ws_size,
                              hipStream_t stream) {
  (void)in_sizes; (void)n_in; (void)out_size; (void)ws_size;
  const float* Q  = (const float*)d_in[0];
  const float* K  = (const float*)d_in[1];
  const float* V  = (const float*)d_in[2];
  const float* tok = (const float*)d_in[3];
  const float* st  = (const float*)d_in[4];
  const float* df  = (const float*)d_in[5];
  const float* cf  = (const float*)d_in[6];
  const int*   msk = (const int*)d_in[8];
  const float* Wq = (const float*)d_in[9];
  const float* bq = (const float*)d_in[10];
  const float* Wk = (const float*)d_in[11];
  const float* bk = (const float*)d_in[12];
  const float* Wv = (const float*)d_in[13];
  const float* bv = (const float*)d_in[14];
  const float* Wo = (const float*)d_in[15];
  const float* bo = (const float*)d_in[16];

  char* ws = (char*)d_ws;
  const size_t MB = 1ull << 20;
  u16* Qbf = (u16*)(ws);
  u16* Kbf = (u16*)(ws + 8 * MB);
  u16* Vbf = (u16*)(ws + 16 * MB);
  u16* Wqb = (u16*)(ws + 24 * MB);
  u16* Wkb = (u16*)(ws + 26 * MB);
  u16* Wvb = (u16*)(ws + 28 * MB);
  u16* Wob = (u16*)(ws + 30 * MB);
  u8*  pkT = (u8*)(ws + 32 * MB);
  u16* Qh  = (u16*)(ws + 36 * MB);
  u16* Kh  = (u16*)(ws + 44 * MB);
  u16* VhT = (u16*)(ws + 52 * MB);
  u16* ctx = (u16*)(ws + 60 * MB);

  cvt3_kernel<<<4096, 256, 0, stream>>>((const float4*)Q, (const float4*)K, (const float4*)V,
                                        (ushort4*)Qbf, (ushort4*)Kbf, (ushort4*)Vbf, 1048576);
  cvt4_kernel<<<1024, 256, 0, stream>>>((const float4*)Wq, (const float4*)Wk, (const float4*)Wv, (const float4*)Wo,
                                        (ushort4*)Wqb, (ushort4*)Wkb, (ushort4*)Wvb, (ushort4*)Wob, 262144);
  pack_kernel<<<dim3(16, 16, 4), 256, 0, stream>>>((const float4*)tok, (const float4*)st, (const float4*)df,
                                                   (const float4*)cf, (const int4*)msk, pkT);
  gemm_bt<0><<<dim3(8, 32), 256, 0, stream>>>(Qbf, Wqb, bq, Qh);
  gemm_bt<0><<<dim3(8, 32), 256, 0, stream>>>(Kbf, Wkb, bk, Kh);
  gemm_bt<2><<<dim3(8, 32), 256, 0, stream>>>(Vbf, Wvb, bv, VhT);
  attn_kernel<<<dim3(8, 64), 256, 0, stream>>>(Qh, Kh, VhT, pkT, ctx);
  gemm_bt<3><<<dim3(8, 32), 256, 0, stream>>>(ctx, Wob, bo, (void*)d_out);
}